// Round 3
// baseline (736.471 us; speedup 1.0000x reference)
//
#include <hip/hip_runtime.h>
#include <math.h>

// ---------------- problem constants ----------------
#define BB 16
#define NBOX 588          // A * 14 * 14
#define TOPJ 392          // J
#define TOPK 196          // K
#define EMBED 768

// ---------------- weight transpose: [Cout][Kin] -> [Kin][Cout] ----------------
__global__ void w_transpose(const float* __restrict__ w, float* __restrict__ wT,
                            int Cout, int Kin) {
    int idx = blockIdx.x * 256 + threadIdx.x;
    if (idx >= Cout * Kin) return;
    int oc = idx % Cout;
    int k  = idx / Cout;
    wT[(long)k * Cout + oc] = w[(long)oc * Kin + k];
}

// ---------------- LDS-tiled implicit-GEMM conv ----------------
// C[M][N] = im2col(in)[M][K] * wT[K][N],  M = B*Hout*Wout, N = Cout, K = Cin*KH*KW
// BM=128 spatial x BN=64 oc x BK=32; 256 threads, 8x4 register tile each.
// Single LDS buffer + register prefetch of next K-chunk (loads overlap compute).
// gridDim.z = K-splits (Ktot % (z*BK) == 0 required); z>0 partials have no bias.
// FUSE: apply y = relu(x*scale[ic] + shift[ic]) to gathered inputs (pre-pad-mask).
#define BM 128
#define BN 64
#define BK 32
template<int KH, int KW, int S, int P, bool FUSE, bool NHWC>
__global__ __launch_bounds__(256) void conv_gemm(
    const float* __restrict__ in, const float* __restrict__ wT,
    const float* __restrict__ bias,
    const float* __restrict__ scale, const float* __restrict__ shift,
    float* __restrict__ out,
    int Cin, int Hin, int Win, int Cout, int Hout, int Wout)
{
    const int KK = KH * KW;
    const int hw = Hout * Wout;
    const long Mtot = (long)BB * hw;
    const int Ktot = Cin * KK;
    const int Kc = Ktot / gridDim.z;
    const int k0 = blockIdx.z * Kc;
    const int n0 = blockIdx.y * BN;
    const long m0 = (long)blockIdx.x * BM;

    __shared__ float As[BK][BM];
    __shared__ float Bs[BK][BN];

    const int tid = threadIdx.x;
    const int tx = tid & 15;        // -> 4 oc
    const int ty = tid >> 4;        // -> 8 sp

    // ---- gather-thread fixed spatial decomposition ----
    const int spl = tid & (BM - 1);
    long sp_g = m0 + spl;
    if (sp_g >= Mtot) sp_g = Mtot - 1;       // clamp (dup loads, stores guarded)
    const int gb  = (int)(sp_g / hw);
    const int gr  = (int)(sp_g - (long)gb * hw);
    const int goy = gr / Wout;
    const int gox = gr - goy * Wout;
    const int kk_off = tid >> 7;             // 0/1 : A-gather k-stride 2
    const int oc_l   = tid & 63;
    const int kb_off = tid >> 6;             // 0..3 : B-gather k-stride 4

    float ra[16], rb[8];

    auto gatherA = [&](int kbase) {
#pragma unroll
        for (int i = 0; i < 16; ++i) {
            int k  = kbase + kk_off + 2 * i;
            int ic = k / KK;
            int rem = k - ic * KK;
            int ky = rem / KW;
            int kx = rem - ky * KW;
            int iy = goy * S - P + ky;
            int ix = gox * S - P + kx;
            float mval = 1.f;
            int iyc = iy, ixc = ix;
            if (P > 0) {
                mval = (iy >= 0 && iy < Hin && ix >= 0 && ix < Win) ? 1.f : 0.f;
                iyc = min(max(iy, 0), Hin - 1);
                ixc = min(max(ix, 0), Win - 1);
            }
            float v = in[((long)(gb * Cin + ic) * Hin + iyc) * Win + ixc];
            if (FUSE) { v = fmaf(v, scale[ic], shift[ic]); v = fmaxf(v, 0.f); }
            if (P > 0) v *= mval;
            ra[i] = v;
        }
    };
    auto gatherB = [&](int kbase) {
#pragma unroll
        for (int j = 0; j < 8; ++j) {
            int k = kbase + kb_off + 4 * j;
            rb[j] = wT[(long)k * Cout + n0 + oc_l];
        }
    };

    float acc[8][4];
    if (blockIdx.z == 0) {
#pragma unroll
        for (int m = 0; m < 8; ++m)
#pragma unroll
            for (int n = 0; n < 4; ++n) acc[m][n] = bias[n0 + tx * 4 + n];
    } else {
#pragma unroll
        for (int m = 0; m < 8; ++m)
#pragma unroll
            for (int n = 0; n < 4; ++n) acc[m][n] = 0.f;
    }

    const int nchunks = Kc / BK;
    gatherA(k0);
    gatherB(k0);

    for (int kc = 0; kc < nchunks; ++kc) {
        // regs -> LDS
#pragma unroll
        for (int i = 0; i < 16; ++i) As[kk_off + 2 * i][spl] = ra[i];
#pragma unroll
        for (int j = 0; j < 8; ++j)  Bs[kb_off + 4 * j][oc_l] = rb[j];
        __syncthreads();
        if (kc + 1 < nchunks) {          // prefetch next chunk into regs
            gatherA(k0 + (kc + 1) * BK);
            gatherB(k0 + (kc + 1) * BK);
        }
        // compute
#pragma unroll
        for (int kk = 0; kk < BK; ++kk) {
            const float4* ap = reinterpret_cast<const float4*>(&As[kk][ty * 8]);
            float4 a0 = ap[0], a1 = ap[1];
            const float4* bp = reinterpret_cast<const float4*>(&Bs[kk][tx * 4]);
            float4 bv = bp[0];
            float av[8] = {a0.x, a0.y, a0.z, a0.w, a1.x, a1.y, a1.z, a1.w};
            float bw[4] = {bv.x, bv.y, bv.z, bv.w};
#pragma unroll
            for (int m = 0; m < 8; ++m)
#pragma unroll
                for (int n = 0; n < 4; ++n)
                    acc[m][n] = fmaf(av[m], bw[n], acc[m][n]);
        }
        __syncthreads();
    }

    // ---- epilogue ----
    const long obase = (long)blockIdx.z * (Mtot * Cout);
#pragma unroll
    for (int m = 0; m < 8; ++m) {
        long sp = m0 + ty * 8 + m;
        if (sp >= Mtot) break;
        if (NHWC) {
            float* op = out + obase + sp * Cout + n0 + tx * 4;
            float4 v = {acc[m][0], acc[m][1], acc[m][2], acc[m][3]};
            *reinterpret_cast<float4*>(op) = v;
        } else {
            int b = (int)(sp / hw);
            int r = (int)(sp - (long)b * hw);
            float* op = out + obase + ((long)b * Cout + n0 + tx * 4) * hw + r;
#pragma unroll
            for (int n = 0; n < 4; ++n) op[(long)n * hw] = acc[m][n];
        }
    }
}

// ---------------- register-blocked direct conv (small-K layers) ----------------
template<int KH, int KW, int S, int P, int OCT, bool FUSE>
__global__ __launch_bounds__(256) void conv_t(
    const float* __restrict__ in, const float* __restrict__ wT,
    const float* __restrict__ bias,
    const float* __restrict__ scale, const float* __restrict__ shift,
    float* __restrict__ out,
    int Cin, int Hin, int Win, int Cout, int Hout, int Wout)
{
    const int  hw    = Hout * Wout;
    const long total = (long)BB * hw;
    long sp = (long)blockIdx.x * 256 + threadIdx.x;
    if (sp >= total) return;
    int b  = (int)(sp / hw);
    int r  = (int)(sp - (long)b * hw);
    int oy = r / Wout;
    int ox = r - oy * Wout;
    int oc0 = blockIdx.y * OCT;

    int icchunk = Cin / gridDim.z;
    int ic0 = blockIdx.z * icchunk;

    float acc[OCT];
    if (blockIdx.z == 0) {
#pragma unroll
        for (int i = 0; i < OCT; ++i) acc[i] = bias[oc0 + i];
    } else {
#pragma unroll
        for (int i = 0; i < OCT; ++i) acc[i] = 0.f;
    }

    int  ixc[KW];
    long yoff[KH];
    float xm[KW], ym[KH];
#pragma unroll
    for (int kx = 0; kx < KW; ++kx) {
        int ix = ox * S - P + kx;
        xm[kx] = (ix >= 0 && ix < Win) ? 1.f : 0.f;
        ixc[kx] = min(max(ix, 0), Win - 1);
    }
#pragma unroll
    for (int ky = 0; ky < KH; ++ky) {
        int iy = oy * S - P + ky;
        ym[ky] = (iy >= 0 && iy < Hin) ? 1.f : 0.f;
        yoff[ky] = (long)min(max(iy, 0), Hin - 1) * Win;
    }

    const float* ib = in + ((long)b * Cin) * Hin * Win;
    for (int ic = ic0; ic < ic0 + icchunk; ++ic) {
        const float* ip = ib + (long)ic * Hin * Win;
        float sc = 0.f, sh = 0.f;
        if (FUSE) { sc = scale[ic]; sh = shift[ic]; }
#pragma unroll
        for (int ky = 0; ky < KH; ++ky) {
            const float* row = ip + yoff[ky];
#pragma unroll
            for (int kx = 0; kx < KW; ++kx) {
                float v = row[ixc[kx]];
                if (FUSE) { v = fmaf(v, sc, sh); v = fmaxf(v, 0.f); }
                if (P > 0) v *= ym[ky] * xm[kx];
                const float* wr = wT + ((long)((ic * KH + ky) * KW + kx)) * Cout + oc0;
#pragma unroll
                for (int i = 0; i < OCT; ++i) acc[i] = fmaf(v, wr[i], acc[i]);
            }
        }
    }

    float* obase = out + (long)blockIdx.z * (total * Cout);
    float* ob = obase + ((long)b * Cout + oc0) * hw + r;
#pragma unroll
    for (int i = 0; i < OCT; ++i) ob[(long)i * hw] = acc[i];
}

// ---------------- deterministic partial-sum reduce ----------------
__global__ void reduce_parts(const float* __restrict__ part, float* __restrict__ out,
                             long n, int nz, long stride) {
    long i = (long)blockIdx.x * 256 + threadIdx.x;
    if (i >= n) return;
    float s = 0.f;
    for (int z = 0; z < nz; ++z) s += part[(long)z * stride + i];
    out[i] = s;
}

// ---------------- BN statistics (deterministic two-stage) ----------------
#define SPLIT 16
__global__ void bn_stats_partial(const float* __restrict__ x, float* __restrict__ psum,
                                 float* __restrict__ psq, int C, int HW) {
    int c    = blockIdx.x / SPLIT;
    int part = blockIdx.x % SPLIT;
    long total = (long)BB * HW;
    float s = 0.f, sq = 0.f;
    for (long t = (long)part * blockDim.x + threadIdx.x; t < total;
         t += (long)SPLIT * blockDim.x) {
        int b = (int)(t / HW);
        int i = (int)(t % HW);
        float v = x[((long)(b * C + c)) * HW + i];
        s += v; sq += v * v;
    }
    for (int o = 32; o > 0; o >>= 1) { s += __shfl_down(s, o); sq += __shfl_down(sq, o); }
    __shared__ float rs[4], rq[4];
    int tid = threadIdx.x;
    if ((tid & 63) == 0) { rs[tid >> 6] = s; rq[tid >> 6] = sq; }
    __syncthreads();
    if (tid == 0) {
        psum[c * SPLIT + part] = rs[0] + rs[1] + rs[2] + rs[3];
        psq [c * SPLIT + part] = rq[0] + rq[1] + rq[2] + rq[3];
    }
}

__global__ void bn_coef(const float* __restrict__ psum, const float* __restrict__ psq,
                        const float* __restrict__ gamma, const float* __restrict__ beta,
                        float* __restrict__ coef, int C, float inv_cnt) {
    int c = blockIdx.x * blockDim.x + threadIdx.x;
    if (c >= C) return;
    float s = 0.f, q = 0.f;
    for (int p = 0; p < SPLIT; ++p) { s += psum[c * SPLIT + p]; q += psq[c * SPLIT + p]; }
    float mean = s * inv_cnt;
    float var  = q * inv_cnt - mean * mean;
    float sc = gamma[c] * rsqrtf(var + 1e-5f);
    coef[c] = sc;                 // scale
    coef[C + c] = beta[c] - mean * sc;  // shift
}

// ---------------- top-K selection (stable ascending rank) + softmax gate ----------------
__global__ void topk_kernel(const float* __restrict__ score, int* __restrict__ sel,
                            float* __restrict__ gate) {
    int b = blockIdx.x;
    int tid = threadIdx.x;
    __shared__ float s[NBOX];
    __shared__ float red[4];
    for (int n = tid; n < NBOX; n += blockDim.x) s[n] = score[b * NBOX + n];
    __syncthreads();

    float mx = -3.0e38f;
    for (int n = tid; n < NBOX; n += blockDim.x) mx = fmaxf(mx, s[n]);
    for (int o = 32; o > 0; o >>= 1) mx = fmaxf(mx, __shfl_down(mx, o));
    if ((tid & 63) == 0) red[tid >> 6] = mx;
    __syncthreads();
    mx = fmaxf(fmaxf(red[0], red[1]), fmaxf(red[2], red[3]));
    __syncthreads();

    float se = 0.f;
    for (int n = tid; n < NBOX; n += blockDim.x) se += expf(s[n] - mx);
    for (int o = 32; o > 0; o >>= 1) se += __shfl_down(se, o);
    if ((tid & 63) == 0) red[tid >> 6] = se;
    __syncthreads();
    se = red[0] + red[1] + red[2] + red[3];

    for (int n = tid; n < NBOX; n += blockDim.x) {
        float v = s[n];
        int rank = 0;
        for (int m = 0; m < NBOX; ++m) {
            float u = s[m];
            rank += (u < v) || (u == v && m < n);
        }
        if (rank >= TOPJ) {
            int k = rank - TOPJ;
            float p = expf(v - mx) / se;
            sel [b * TOPK + k] = n;
            gate[b * TOPK + k] = (1.0f - p) + p;
        }
    }
}

// ---------------- ROI align 1x1 + gate (e3 is NHWC) ----------------
__global__ void roi_gather(const float* __restrict__ e3, const int* __restrict__ sel,
                           const float* __restrict__ gate, float* __restrict__ out) {
    int bk = blockIdx.x;                 // b*196 + k
    int b = bk / TOPK;
    int n = sel[bk];
    float gt = gate[bk];
    int a   = n / 196;
    int pos = n % 196;
    int i = pos / 14;
    int j = pos % 14;
    int S = a + 1;
    float inv_cnt = 1.0f / (float)(S * S);

    __shared__ int   cidx[9][4];
    __shared__ float cw  [9][4];
    if (threadIdx.x == 0) {
        int t = 0;
        for (int p = 0; p < S; ++p) {
            float yy = (float)j - S * 0.5f + p + 0.5f;   // row coord from j
            float yc = fmaxf(yy, 0.0f);
            int yf = (int)floorf(yc);
            int y_lo, y_hi; float ly;
            if (yf >= 13) { y_lo = 13; y_hi = 13; ly = 0.f; }
            else          { y_lo = yf; y_hi = yf + 1; ly = yc - (float)yf; }
            for (int q = 0; q < S; ++q) {
                float xx = (float)i - S * 0.5f + q + 0.5f;  // col coord from i
                float xc = fmaxf(xx, 0.0f);
                int xf = (int)floorf(xc);
                int x_lo, x_hi; float lx;
                if (xf >= 13) { x_lo = 13; x_hi = 13; lx = 0.f; }
                else          { x_lo = xf; x_hi = xf + 1; lx = xc - (float)xf; }
                cidx[t][0] = y_lo * 14 + x_lo;  cw[t][0] = (1.f - ly) * (1.f - lx);
                cidx[t][1] = y_lo * 14 + x_hi;  cw[t][1] = (1.f - ly) * lx;
                cidx[t][2] = y_hi * 14 + x_lo;  cw[t][2] = ly * (1.f - lx);
                cidx[t][3] = y_hi * 14 + x_hi;  cw[t][3] = ly * lx;
                ++t;
            }
        }
    }
    __syncthreads();
    int NS = S * S;
    const float* base = e3 + (long)b * 196 * EMBED;
    for (int c = threadIdx.x; c < EMBED; c += blockDim.x) {
        float acc = 0.f;
        for (int t = 0; t < NS; ++t) {
            acc += cw[t][0] * base[cidx[t][0] * EMBED + c]
                 + cw[t][1] * base[cidx[t][1] * EMBED + c]
                 + cw[t][2] * base[cidx[t][2] * EMBED + c]
                 + cw[t][3] * base[cidx[t][3] * EMBED + c];
        }
        out[(long)bk * EMBED + c] = acc * inv_cnt * gt;
    }
}

// ---------------- host launch ----------------
extern "C" void kernel_launch(void* const* d_in, const int* in_sizes, int n_in,
                              void* d_out, int out_size, void* d_ws, size_t ws_size,
                              hipStream_t stream) {
    const float* x   = (const float*)d_in[0];
    const float* pw1 = (const float*)d_in[1];
    const float* pb1 = (const float*)d_in[2];
    const float* pw2 = (const float*)d_in[3];
    const float* pb2 = (const float*)d_in[4];
    const float* pw3 = (const float*)d_in[5];
    const float* pb3 = (const float*)d_in[6];
    const float* rw1 = (const float*)d_in[7];
    const float* rb1 = (const float*)d_in[8];
    const float* g1  = (const float*)d_in[9];
    const float* b1  = (const float*)d_in[10];
    const float* rw2 = (const float*)d_in[11];
    const float* rb2 = (const float*)d_in[12];
    const float* g2  = (const float*)d_in[13];
    const float* b2  = (const float*)d_in[14];
    const float* rw3 = (const float*)d_in[15];
    const float* rb3 = (const float*)d_in[16];
    const float* g3  = (const float*)d_in[17];
    const float* b3  = (const float*)d_in[18];
    const float* rw4 = (const float*)d_in[19];
    const float* rb4 = (const float*)d_in[20];

    float* ws = (float*)d_ws;
    // region A: r1 (16,64,112,112); later rp3/patch2 partials; later e3 NHWC
    const long SZ_A = 16L * 64 * 112 * 112;
    // region B: r2 (16,128,56,56); later rp4 partials; later e1; later patch3 partials
    const long SZ_B = 16L * 128 * 56 * 56;
    // region C: r3 (16,256,28,28); later e2
    const long SZ_C = 16L * 256 * 28 * 28;
    const long OFF_A = 0;
    const long OFF_B = OFF_A + SZ_A;
    const long OFF_C = OFF_B + SZ_B;
    const long OFF_SCORE = OFF_C + SZ_C;
    const long OFF_PS = OFF_SCORE + 16L * NBOX;
    const long OFF_PQ = OFF_PS + 256L * SPLIT;
    const long OFF_CO = OFF_PQ + 256L * SPLIT;
    const long OFF_GATE = OFF_CO + 1024;
    const long OFF_SEL  = OFF_GATE + 16L * TOPK;

    float* r1 = ws + OFF_A;
    float* r2 = ws + OFF_B;
    float* r3 = ws + OFF_C;
    float* e3 = ws + OFF_A;
    float* e1 = ws + OFF_B;
    float* e2 = ws + OFF_C;
    float* partA = ws + OFF_A;            // rp3 / patch2 partials
    float* partB = ws + OFF_B;            // rp4 / patch3 partials
    float* score = ws + OFF_SCORE;
    float* psum  = ws + OFF_PS;
    float* psq   = ws + OFF_PQ;
    float* coef  = ws + OFF_CO;           // [scale(C); shift(C)]
    float* gate  = ws + OFF_GATE;
    int*   sel   = (int*)(ws + OFF_SEL);

    // transposed weights live in d_out (fully overwritten by roi_gather at the end)
    float* dout = (float*)d_out;
    float* t_rw1 = dout;                      // 64*27
    float* t_rw2 = t_rw1 + 64L * 27;          // 128*576
    float* t_rw3 = t_rw2 + 128L * 576;        // 256*1152
    float* t_rw4 = t_rw3 + 256L * 1152;       // 3*2304
    float* t_pw1 = t_rw4 + 3L * 2304;         // 64*48
    float* t_pw2 = t_pw1 + 64L * 48;          // 128*256
    float* t_pw3 = t_pw2 + 128L * 256;        // 768*512 (end 806336 < out_size)

    const int T = 256;
    auto tw = [&](const float* w, float* wT, int Cout, int Kin) {
        int n = Cout * Kin;
        w_transpose<<<(n + T - 1) / T, T, 0, stream>>>(w, wT, Cout, Kin);
    };
    tw(rw1, t_rw1, 64, 27);
    tw(rw2, t_rw2, 128, 576);
    tw(rw3, t_rw3, 256, 1152);
    tw(rw4, t_rw4, 3, 2304);
    tw(pw1, t_pw1, 64, 48);
    tw(pw2, t_pw2, 128, 256);
    tw(pw3, t_pw3, 768, 512);

    // ---- region-proposal path (fp32: argsort order must match) ----
    // rp1: (16,3,224,224) -> raw r1 (16,64,112,112)
    conv_t<3,3,2,1,8,false><<<dim3(784, 8, 1), T, 0, stream>>>(
        x, t_rw1, rb1, nullptr, nullptr, r1, 3, 224, 224, 64, 112, 112);
    bn_stats_partial<<<64 * SPLIT, T, 0, stream>>>(r1, psum, psq, 64, 112 * 112);
    bn_coef<<<1, T, 0, stream>>>(psum, psq, g1, b1, coef, 64, 1.0f / (16.f * 112 * 112));

    // rp2: bn1+relu fused on gather -> raw r2 (16,128,56,56)
    conv_gemm<3,3,2,1,true,false><<<dim3(392, 2, 1), T, 0, stream>>>(
        r1, t_rw2, rb2, coef, coef + 64, r2, 64, 112, 112, 128, 56, 56);
    bn_stats_partial<<<128 * SPLIT, T, 0, stream>>>(r2, psum, psq, 128, 56 * 56);
    bn_coef<<<1, T, 0, stream>>>(psum, psq, g2, b2, coef, 128, 1.0f / (16.f * 56 * 56));

    // rp3: bn2+relu fused, split-K=2, partials in region A (r1 dead) -> raw r3
    conv_gemm<3,3,2,1,true,false><<<dim3(98, 4, 2), T, 0, stream>>>(
        r2, t_rw3, rb3, coef, coef + 128, partA, 128, 56, 56, 256, 28, 28);
    {
        long n = 16L * 256 * 28 * 28;
        reduce_parts<<<(int)((n + T - 1) / T), T, 0, stream>>>(partA, r3, n, 2, n);
    }
    bn_stats_partial<<<256 * SPLIT, T, 0, stream>>>(r3, psum, psq, 256, 28 * 28);
    bn_coef<<<1, T, 0, stream>>>(psum, psq, g3, b3, coef, 256, 1.0f / (16.f * 28 * 28));

    // rp4 (score): bn3+relu fused, split-K=8 direct, partials in region B (r2 dead)
    conv_t<3,3,2,1,3,true><<<dim3(13, 1, 8), T, 0, stream>>>(
        r3, t_rw4, rb4, coef, coef + 256, partB, 256, 28, 28, 3, 14, 14);
    reduce_parts<<<(9408 + T - 1) / T, T, 0, stream>>>(partB, score, 9408, 8, 9408);

    // top-K + gate
    topk_kernel<<<16, T, 0, stream>>>(score, sel, gate);

    // ---- patch-embed path ----
    // patch1: x -> e1 (16,64,56,56)  [region B free: rp4 partials consumed]
    conv_t<4,4,4,0,8,false><<<dim3(196, 8, 1), T, 0, stream>>>(
        x, t_pw1, pb1, nullptr, nullptr, e1, 3, 224, 224, 64, 56, 56);
    // patch2: e1 -> e2 (16,128,28,28), split-K=2, partials region A (rp3 parts consumed)
    conv_gemm<2,2,2,0,false,false><<<dim3(98, 2, 2), T, 0, stream>>>(
        e1, t_pw2, pb2, nullptr, nullptr, partA, 64, 56, 56, 128, 28, 28);
    {
        long n = 16L * 128 * 28 * 28;
        reduce_parts<<<(int)((n + T - 1) / T), T, 0, stream>>>(partA, e2, n, 2, n);
    }
    // patch3: e2 -> e3 NHWC (16,196,768), split-K=2, partials region B (e1 dead)
    conv_gemm<2,2,2,0,false,true><<<dim3(25, 12, 2), T, 0, stream>>>(
        e2, t_pw3, pb3, nullptr, nullptr, partB, 128, 28, 28, 768, 14, 14);
    {
        long n = 16L * 196 * 768;
        reduce_parts<<<(int)((n + T - 1) / T), T, 0, stream>>>(partB, e3, n, 2, n);
    }

    // ---- ROI align + gate -> d_out (16,196,768) ----
    roi_gather<<<16 * TOPK, T, 0, stream>>>(e3, sel, gate, dout);
}